// Round 5
// baseline (143.601 us; speedup 1.0000x reference)
//
#include <hip/hip_runtime.h>

// log1p thresholds (fp32): ln(6), ln(26), ln(51)
#define THR1 1.7917594909667969f
#define THR2 3.2580966949462891f
#define THR3 3.9318256378173828f
#define W1 0.2f
#define W2 30.0f
#define W3 2500.0f
#define W4 20000.0f

#define BLOCK 256
#define UNROLL 4                   // float4-pairs per chunk per thread
#define GRID 1280                  // 3,932,160 float4 / (256*4) = 3840 chunks = 1280 * 3

typedef float f4 __attribute__((ext_vector_type(4)));

__device__ __forceinline__ float bucket_w(float y) {
    return (y < THR1) ? W1 : ((y < THR2) ? W2 : ((y < THR3) ? W3 : W4));
}

__device__ __forceinline__ void accum4(const f4 a, const f4 b, float& num, float& den) {
    #pragma unroll
    for (int e = 0; e < 4; ++e) {
        const float w = bucket_w(b[e]);
        num += w * fabsf(b[e] - a[e]);
        den += w;
    }
}

__device__ __forceinline__ void prefetch_chunk(const f4* __restrict__ p4,
                                               const f4* __restrict__ t4,
                                               int base, f4* a, f4* b) {
    #pragma unroll
    for (int k = 0; k < UNROLL; ++k) a[k] = __builtin_nontemporal_load(p4 + base + k * BLOCK);
    #pragma unroll
    for (int k = 0; k < UNROLL; ++k) b[k] = __builtin_nontemporal_load(t4 + base + k * BLOCK);
}

__global__ __launch_bounds__(BLOCK) void mae_stage1(
    const float* __restrict__ y_pred,
    const float* __restrict__ y_true,
    float2* __restrict__ partials,   // one (num,den) per block
    int n)
{
    const int n4 = n >> 2;
    const int CHUNK = BLOCK * UNROLL;        // 1024 float4s per chunk
    const int nchunks = n4 / CHUNK;          // 3840 (exact for this problem)
    const f4* __restrict__ p4 = (const f4*)y_pred;
    const f4* __restrict__ t4 = (const f4*)y_true;

    float num = 0.0f, den = 0.0f;

    // 2-deep software pipeline over chunks: prefetch c+GRID while consuming c.
    // All branches are wave-uniform (c, nchunks are uniform) -> no lane masks.
    f4 A[2][UNROLL], B[2][UNROLL];
    int c = blockIdx.x;
    int buf = 0;
    if (c < nchunks)
        prefetch_chunk(p4, t4, c * CHUNK + threadIdx.x, A[0], B[0]);
    for (; c < nchunks; c += GRID) {
        const int cn = c + GRID;
        if (cn < nchunks)
            prefetch_chunk(p4, t4, cn * CHUNK + threadIdx.x, A[buf ^ 1], B[buf ^ 1]);
        #pragma unroll
        for (int k = 0; k < UNROLL; ++k) accum4(A[buf][k], B[buf][k], num, den);
        buf ^= 1;
    }

    // tail: elements beyond full chunks (zero for this problem shape)
    const int tail_start = nchunks * CHUNK * 4;   // element index
    for (int j = tail_start + blockIdx.x * BLOCK + threadIdx.x; j < n;
         j += GRID * BLOCK) {
        const float aa = y_pred[j];
        const float bb = y_true[j];
        const float w = bucket_w(bb);
        num += w * fabsf(bb - aa);
        den += w;
    }

    // 64-lane wave reduction
    #pragma unroll
    for (int off = 32; off > 0; off >>= 1) {
        num += __shfl_down(num, off, 64);
        den += __shfl_down(den, off, 64);
    }

    __shared__ float s_num[4];
    __shared__ float s_den[4];
    const int wave = threadIdx.x >> 6;
    const int lane = threadIdx.x & 63;
    if (lane == 0) { s_num[wave] = num; s_den[wave] = den; }
    __syncthreads();

    if (threadIdx.x == 0) {
        partials[blockIdx.x] = make_float2(s_num[0] + s_num[1] + s_num[2] + s_num[3],
                                           s_den[0] + s_den[1] + s_den[2] + s_den[3]);
    }
}

__global__ __launch_bounds__(BLOCK) void mae_stage2(
    const float2* __restrict__ partials, int nblocks, float* __restrict__ out)
{
    float num = 0.0f, den = 0.0f;
    for (int i = threadIdx.x; i < nblocks; i += BLOCK) {
        const float2 v = partials[i];
        num += v.x; den += v.y;
    }

    #pragma unroll
    for (int off = 32; off > 0; off >>= 1) {
        num += __shfl_down(num, off, 64);
        den += __shfl_down(den, off, 64);
    }

    __shared__ float s_num[4];
    __shared__ float s_den[4];
    const int wave = threadIdx.x >> 6;
    const int lane = threadIdx.x & 63;
    if (lane == 0) { s_num[wave] = num; s_den[wave] = den; }
    __syncthreads();

    if (threadIdx.x == 0) {
        const float bn = s_num[0] + s_num[1] + s_num[2] + s_num[3];
        const float bd = s_den[0] + s_den[1] + s_den[2] + s_den[3];
        out[0] = bn / bd;
    }
}

extern "C" void kernel_launch(void* const* d_in, const int* in_sizes, int n_in,
                              void* d_out, int out_size, void* d_ws, size_t ws_size,
                              hipStream_t stream)
{
    const float* y_pred = (const float*)d_in[0];
    const float* y_true = (const float*)d_in[1];
    float* out = (float*)d_out;
    float2* partials = (float2*)d_ws;       // GRID float2s, fully overwritten each call
    const int n = in_sizes[0];

    mae_stage1<<<GRID, BLOCK, 0, stream>>>(y_pred, y_true, partials, n);
    mae_stage2<<<1, BLOCK, 0, stream>>>(partials, GRID, out);
}

// Round 6
// 141.837 us; speedup vs baseline: 1.0124x; 1.0124x over previous
//
#include <hip/hip_runtime.h>

// log1p thresholds (fp32): ln(6), ln(26), ln(51)
#define THR1 1.7917594909667969f
#define THR2 3.2580966949462891f
#define THR3 3.9318256378173828f
#define W1 0.2f
#define W2 30.0f
#define W3 2500.0f
#define W4 20000.0f

#define BLOCK 256
#define TILE 1024        // float4 per stream per buffer = 16 KB
#define GRID 512         // 2 blocks/CU (64 KB LDS each) x 256 CUs

typedef float f4 __attribute__((ext_vector_type(4)));

__device__ __forceinline__ float bucket_w(float y) {
    return (y < THR1) ? W1 : ((y < THR2) ? W2 : ((y < THR3) ? W3 : W4));
}

__device__ __forceinline__ void accum4(const f4 a, const f4 b, float& num, float& den) {
    #pragma unroll
    for (int e = 0; e < 4; ++e) {
        const float w = bucket_w(b[e]);
        num += w * fabsf(b[e] - a[e]);
        den += w;
    }
}

__global__ __launch_bounds__(BLOCK) void mae_stage1(
    const float* __restrict__ y_pred,
    const float* __restrict__ y_true,
    float2* __restrict__ partials,
    int n)
{
    const int n4 = n >> 2;
    const int nch = n4 / TILE;               // 3840 for this problem (exact)
    const f4* __restrict__ p4 = (const f4*)y_pred;
    const f4* __restrict__ t4 = (const f4*)y_true;

    // double-buffered DMA tiles: 2 streams x 2 buffers x 16 KB = 64 KB
    __shared__ f4 sp[2][TILE];
    __shared__ f4 st[2][TILE];

    const int tid  = threadIdx.x;
    const int wave = tid >> 6;

    // stage chunk c into buffer b via global_load_lds (DMA, bypasses VGPR path).
    // LDS dest must be wave-uniform base; HW adds lane*16.
    #define STAGE(b, c)                                                          \
        do {                                                                     \
            const f4* gp = p4 + (c) * TILE;                                      \
            const f4* gt = t4 + (c) * TILE;                                      \
            _Pragma("unroll")                                                    \
            for (int k = 0; k < 4; ++k) {                                        \
                __builtin_amdgcn_global_load_lds(                                \
                    (const __attribute__((address_space(1))) void*)(gp + k * 256 + tid), \
                    (__attribute__((address_space(3))) void*)&sp[b][k * 256 + wave * 64], \
                    16, 0, 0);                                                   \
                __builtin_amdgcn_global_load_lds(                                \
                    (const __attribute__((address_space(1))) void*)(gt + k * 256 + tid), \
                    (__attribute__((address_space(3))) void*)&st[b][k * 256 + wave * 64], \
                    16, 0, 0);                                                   \
            }                                                                    \
        } while (0)

    float num = 0.0f, den = 0.0f;

    int c = blockIdx.x;
    int buf = 0;
    if (c < nch) STAGE(0, c);

    for (; c < nch; c += GRID) {
        // full drain: current buf's DMA complete, all waves aligned
        __syncthreads();

        const int cn = c + GRID;
        if (cn < nch) STAGE(buf ^ 1, cn);    // next tile's DMA overlaps compute below

        #pragma unroll
        for (int j = 0; j < 4; ++j) {
            const f4 a = sp[buf][j * 256 + tid];
            const f4 b = st[buf][j * 256 + tid];
            accum4(a, b, num, den);
        }

        // raw barrier: order waves without draining the in-flight next-tile DMA.
        // ds_read results are already consumed into num/den (data dependency),
        // so no wave has outstanding reads of buf when another overwrites it
        // (overwrite of buf happens only after the NEXT __syncthreads anyway).
        asm volatile("s_barrier" ::: "memory");
        buf ^= 1;
    }

    // tail: elements beyond full tiles (zero for this problem shape)
    const int tail_start = nch * TILE * 4;
    for (int j = tail_start + (int)blockIdx.x * BLOCK + tid; j < n; j += GRID * BLOCK) {
        const float aa = y_pred[j];
        const float bb = y_true[j];
        const float w = bucket_w(bb);
        num += w * fabsf(bb - aa);
        den += w;
    }

    // 64-lane wave reduction
    #pragma unroll
    for (int off = 32; off > 0; off >>= 1) {
        num += __shfl_down(num, off, 64);
        den += __shfl_down(den, off, 64);
    }

    __shared__ float s_num[4];
    __shared__ float s_den[4];
    const int lane = tid & 63;
    if (lane == 0) { s_num[wave] = num; s_den[wave] = den; }
    __syncthreads();

    if (tid == 0) {
        partials[blockIdx.x] = make_float2(s_num[0] + s_num[1] + s_num[2] + s_num[3],
                                           s_den[0] + s_den[1] + s_den[2] + s_den[3]);
    }
}

__global__ __launch_bounds__(BLOCK) void mae_stage2(
    const float2* __restrict__ partials, int nblocks, float* __restrict__ out)
{
    float num = 0.0f, den = 0.0f;
    for (int i = threadIdx.x; i < nblocks; i += BLOCK) {
        const float2 v = partials[i];
        num += v.x; den += v.y;
    }

    #pragma unroll
    for (int off = 32; off > 0; off >>= 1) {
        num += __shfl_down(num, off, 64);
        den += __shfl_down(den, off, 64);
    }

    __shared__ float s_num[4];
    __shared__ float s_den[4];
    const int wave = threadIdx.x >> 6;
    const int lane = threadIdx.x & 63;
    if (lane == 0) { s_num[wave] = num; s_den[wave] = den; }
    __syncthreads();

    if (threadIdx.x == 0) {
        const float bn = s_num[0] + s_num[1] + s_num[2] + s_num[3];
        const float bd = s_den[0] + s_den[1] + s_den[2] + s_den[3];
        out[0] = bn / bd;
    }
}

extern "C" void kernel_launch(void* const* d_in, const int* in_sizes, int n_in,
                              void* d_out, int out_size, void* d_ws, size_t ws_size,
                              hipStream_t stream)
{
    const float* y_pred = (const float*)d_in[0];
    const float* y_true = (const float*)d_in[1];
    float* out = (float*)d_out;
    float2* partials = (float2*)d_ws;       // GRID float2s, fully overwritten each call
    const int n = in_sizes[0];

    mae_stage1<<<GRID, BLOCK, 0, stream>>>(y_pred, y_true, partials, n);
    mae_stage2<<<1, BLOCK, 0, stream>>>(partials, GRID, out);
}

// Round 7
// 141.457 us; speedup vs baseline: 1.0152x; 1.0027x over previous
//
#include <hip/hip_runtime.h>

// log1p thresholds (fp32): ln(6), ln(26), ln(51)
#define THR1 1.7917594909667969f
#define THR2 3.2580966949462891f
#define THR3 3.9318256378173828f
#define W1 0.2f
#define W2 30.0f
#define W3 2500.0f
#define W4 20000.0f

#define BLOCK 256
#define UNROLL 4                   // float4-pairs per thread per chunk
#define GRID 1280                  // 5 blocks/CU; 3840 chunks / 1280 = 3 iters exact
// NOTE (R3-R6 evidence): read-only kernels plateau at ~3.0 TB/s effective on
// this part (write-only hits 6.5 TB/s; copy read-side 3.15 TB/s) — a read-
// return fabric ceiling. VGPR loads, LDS-DMA (global_load_lds), nontemporal,
// and deeper MLP all measured identical. This structure is the simplest one
// that reaches the ceiling: exact tiling, no predication, no atomics.

__device__ __forceinline__ float bucket_w(float y) {
    return (y < THR1) ? W1 : ((y < THR2) ? W2 : ((y < THR3) ? W3 : W4));
}

__device__ __forceinline__ void accum(float4 a, float4 b, float& num, float& den) {
    float w;
    w = bucket_w(b.x); num += w * fabsf(b.x - a.x); den += w;
    w = bucket_w(b.y); num += w * fabsf(b.y - a.y); den += w;
    w = bucket_w(b.z); num += w * fabsf(b.z - a.z); den += w;
    w = bucket_w(b.w); num += w * fabsf(b.w - a.w); den += w;
}

__global__ __launch_bounds__(BLOCK) void mae_stage1(
    const float* __restrict__ y_pred,
    const float* __restrict__ y_true,
    float2* __restrict__ partials,   // one (num,den) per block
    int n)
{
    const int n4 = n >> 2;
    const int CHUNK = BLOCK * UNROLL;        // 1024 float4s per chunk
    const int nchunks = n4 / CHUNK;          // full chunks (exact for this problem)
    const float4* __restrict__ p4 = (const float4*)y_pred;
    const float4* __restrict__ t4 = (const float4*)y_true;

    float num = 0.0f, den = 0.0f;

    // steady state: NO bounds checks -> 8 independent 16B loads in flight
    for (int c = blockIdx.x; c < nchunks; c += gridDim.x) {
        const int base = c * CHUNK + threadIdx.x;
        const float4 a0 = p4[base + 0 * BLOCK];
        const float4 a1 = p4[base + 1 * BLOCK];
        const float4 a2 = p4[base + 2 * BLOCK];
        const float4 a3 = p4[base + 3 * BLOCK];
        const float4 b0 = t4[base + 0 * BLOCK];
        const float4 b1 = t4[base + 1 * BLOCK];
        const float4 b2 = t4[base + 2 * BLOCK];
        const float4 b3 = t4[base + 3 * BLOCK];
        accum(a0, b0, num, den);
        accum(a1, b1, num, den);
        accum(a2, b2, num, den);
        accum(a3, b3, num, den);
    }

    // tail: any elements beyond the full chunks (zero for this problem shape)
    const int tail_start = nchunks * CHUNK * 4;   // element index
    for (int j = tail_start + blockIdx.x * BLOCK + threadIdx.x; j < n;
         j += gridDim.x * BLOCK) {
        const float aa = y_pred[j];
        const float bb = y_true[j];
        const float w = bucket_w(bb);
        num += w * fabsf(bb - aa);
        den += w;
    }

    // 64-lane wave reduction
    #pragma unroll
    for (int off = 32; off > 0; off >>= 1) {
        num += __shfl_down(num, off, 64);
        den += __shfl_down(den, off, 64);
    }

    __shared__ float s_num[4];
    __shared__ float s_den[4];
    const int wave = threadIdx.x >> 6;
    const int lane = threadIdx.x & 63;
    if (lane == 0) { s_num[wave] = num; s_den[wave] = den; }
    __syncthreads();

    if (threadIdx.x == 0) {
        partials[blockIdx.x] = make_float2(s_num[0] + s_num[1] + s_num[2] + s_num[3],
                                           s_den[0] + s_den[1] + s_den[2] + s_den[3]);
    }
}

__global__ __launch_bounds__(BLOCK) void mae_stage2(
    const float2* __restrict__ partials, int nblocks, float* __restrict__ out)
{
    float num = 0.0f, den = 0.0f;
    for (int i = threadIdx.x; i < nblocks; i += BLOCK) {
        const float2 v = partials[i];
        num += v.x; den += v.y;
    }

    #pragma unroll
    for (int off = 32; off > 0; off >>= 1) {
        num += __shfl_down(num, off, 64);
        den += __shfl_down(den, off, 64);
    }

    __shared__ float s_num[4];
    __shared__ float s_den[4];
    const int wave = threadIdx.x >> 6;
    const int lane = threadIdx.x & 63;
    if (lane == 0) { s_num[wave] = num; s_den[wave] = den; }
    __syncthreads();

    if (threadIdx.x == 0) {
        const float bn = s_num[0] + s_num[1] + s_num[2] + s_num[3];
        const float bd = s_den[0] + s_den[1] + s_den[2] + s_den[3];
        out[0] = bn / bd;
    }
}

extern "C" void kernel_launch(void* const* d_in, const int* in_sizes, int n_in,
                              void* d_out, int out_size, void* d_ws, size_t ws_size,
                              hipStream_t stream)
{
    const float* y_pred = (const float*)d_in[0];
    const float* y_true = (const float*)d_in[1];
    float* out = (float*)d_out;
    float2* partials = (float2*)d_ws;       // GRID float2s, fully overwritten each call
    const int n = in_sizes[0];

    mae_stage1<<<GRID, BLOCK, 0, stream>>>(y_pred, y_true, partials, n);
    mae_stage2<<<1, BLOCK, 0, stream>>>(partials, GRID, out);
}